// Round 6
// baseline (365.333 us; speedup 1.0000x reference)
//
#include <hip/hip_runtime.h>
#include <stdint.h>

#define DD 160
#define HH 160
#define WW 160
#define NGRID (DD*HH*WW)        // 4,096,000
#define NCHUNK (NGRID/1024)     // 4000 chunks of 1024 cells
#define CIN 32
#define COUT 64
#define KK 27
#define BLOCK 1024
#define WPB 16
#define NBLOCKS 256
#define TOTW (NBLOCKS*WPB)      // 4096 waves
#define M27 0x07FFFFFFu

typedef _Float16 h2_t __attribute__((ext_vector_type(2)));

__device__ __forceinline__ h2_t as_h2(uint32_t u) {
    union { uint32_t u; h2_t h; } c; c.u = u; return c.h;
}
__device__ __forceinline__ uint32_t f2h(float f) {
    union { _Float16 h; uint16_t u; } c; c.h = (_Float16)f; return (uint32_t)c.u;
}

// 2-wide f16 dot with f32 accumulate: v_dot2_f32_f16
__device__ __forceinline__ float dot2(uint32_t fu, uint32_t wu, float acc) {
#if defined(__has_builtin)
#if __has_builtin(__builtin_amdgcn_fdot2)
    return __builtin_amdgcn_fdot2(as_h2(fu), as_h2(wu), acc, false);
#else
    h2_t f = as_h2(fu), w = as_h2(wu);
    acc = fmaf((float)f.x, (float)w.x, acc);
    return fmaf((float)f.y, (float)w.y, acc);
#endif
#else
    h2_t f = as_h2(fu), w = as_h2(wu);
    acc = fmaf((float)f.x, (float)w.x, acc);
    return fmaf((float)f.y, (float)w.y, acc);
#endif
}

// k1: scatter orig ids into dense grid + per-chunk counts + weight pack
__global__ void scatter_pack(const int4* __restrict__ coors, const float* __restrict__ w,
                             int* __restrict__ grid, int* __restrict__ cnt,
                             uint4* __restrict__ wpk, int n)
{
    int gid = blockIdx.x * 256 + threadIdx.x;
    if (gid < n) {
        int4 c = coors[gid];
        int cell = (c.y*HH + c.z)*WW + c.w;
        grid[cell] = gid;
        atomicAdd(&cnt[cell >> 10], 1);
    } else if (gid < n + KK*4*COUT) {
        int t = gid - n;
        int co = t & 63;
        int g  = (t >> 6) & 3;
        int k  = t >> 8;
        const float* base = w + (size_t)k*CIN*COUT + (size_t)(8*g)*COUT + co;
        uint4 r;
        r.x = f2h(base[0*COUT]) | (f2h(base[1*COUT]) << 16);
        r.y = f2h(base[2*COUT]) | (f2h(base[3*COUT]) << 16);
        r.z = f2h(base[4*COUT]) | (f2h(base[5*COUT]) << 16);
        r.w = f2h(base[6*COUT]) | (f2h(base[7*COUT]) << 16);
        wpk[t] = r;
    }
}

// k2: exclusive scan of the 4000 chunk counts (single 1024-thread block)
__global__ __launch_bounds__(1024) void scan_chunks(const int* __restrict__ cnt,
                                                    int* __restrict__ base)
{
    __shared__ int s[1024];
    int t = threadIdx.x;
    int c0 = 0, c1 = 0, c2 = 0, c3 = 0, sum;
    int i0 = t * 4;
    if (i0 + 3 < NCHUNK) { c0 = cnt[i0]; c1 = cnt[i0+1]; c2 = cnt[i0+2]; c3 = cnt[i0+3]; }
    else {
        if (i0     < NCHUNK) c0 = cnt[i0];
        if (i0 + 1 < NCHUNK) c1 = cnt[i0+1];
        if (i0 + 2 < NCHUNK) c2 = cnt[i0+2];
        if (i0 + 3 < NCHUNK) c3 = cnt[i0+3];
    }
    sum = c0 + c1 + c2 + c3;
    s[t] = sum; __syncthreads();
    for (int off = 1; off < 1024; off <<= 1) {
        int val = (t >= off) ? s[t - off] : 0;
        __syncthreads();
        s[t] += val;
        __syncthreads();
    }
    int excl = s[t] - sum;
    if (i0     < NCHUNK) { base[i0]   = excl; excl += c0; }
    if (i0 + 1 < NCHUNK) { base[i0+1] = excl; excl += c1; }
    if (i0 + 2 < NCHUNK) { base[i0+2] = excl; excl += c2; }
    if (i0 + 3 < NCHUNK) { base[i0+3] = excl; }
}

// k3: ordered compaction (cell order -> sorted position sp) + feature gather/convert
//     grid[cell] is rewritten from orig id -> sp; pos[sp]=cell; om[sp]=orig id.
__global__ __launch_bounds__(1024) void emit_sort(const float4* __restrict__ f4,
                                                  int* __restrict__ grid,
                                                  const int* __restrict__ base,
                                                  int* __restrict__ pos, int* __restrict__ om,
                                                  uint2* __restrict__ fh)
{
    __shared__ int wt[16];
    int cell = blockIdx.x * 1024 + threadIdx.x;   // gridDim = NCHUNK, always < NGRID
    int g = grid[cell];
    bool pres = g >= 0;
    unsigned long long bal = __ballot(pres);
    int lane = threadIdx.x & 63;
    int wv = threadIdx.x >> 6;
    int lpre = __popcll(bal & ((1ull << lane) - 1ull));
    if (lane == 0) wt[wv] = __popcll(bal);
    __syncthreads();
    if (threadIdx.x == 0) {
        int acc = 0;
        for (int i = 0; i < 16; ++i) { int c = wt[i]; wt[i] = acc; acc += c; }
    }
    __syncthreads();
    if (pres) {
        int sp = base[blockIdx.x] + wt[wv] + lpre;
        pos[sp] = cell;
        om[sp]  = g;
        grid[cell] = sp;
        const float4* src = f4 + (size_t)g * 8;
        uint2* dst = fh + (size_t)sp * 8;
        #pragma unroll
        for (int q = 0; q < 8; ++q) {
            float4 vv = src[q];
            uint2 r;
            r.x = f2h(vv.x) | (f2h(vv.y) << 16);
            r.y = f2h(vv.z) | (f2h(vv.w) << 16);
            dst[q] = r;
        }
    }
}

// load 4x uint4 (32 f16 feats = one row) broadcast from sorted row j
#define LOAD4(D0,D1,D2,D3,J) { \
    const uint4* fp_ = fh4 + (size_t)(J) * 4; \
    D0 = fp_[0]; D1 = fp_[1]; D2 = fp_[2]; D3 = fp_[3]; }

// 16 v_dot2_f32_f16 against LDS weights for tap kk
#define MAC4(F0,F1,F2,F3,kk) { \
    const uint4* wl_ = wlds + (size_t)(kk)*4*COUT + lane; \
    uint4 w0_ = wl_[0], w1_ = wl_[COUT], w2_ = wl_[2*COUT], w3_ = wl_[3*COUT]; \
    a0 = dot2(F0.x, w0_.x, a0); a1 = dot2(F0.y, w0_.y, a1); \
    a2 = dot2(F0.z, w0_.z, a2); a3 = dot2(F0.w, w0_.w, a3); \
    a0 = dot2(F1.x, w1_.x, a0); a1 = dot2(F1.y, w1_.y, a1); \
    a2 = dot2(F1.z, w1_.z, a2); a3 = dot2(F1.w, w1_.w, a3); \
    a0 = dot2(F2.x, w2_.x, a0); a1 = dot2(F2.y, w2_.y, a1); \
    a2 = dot2(F2.z, w2_.z, a2); a3 = dot2(F2.w, w2_.w, a3); \
    a0 = dot2(F3.x, w3_.x, a0); a1 = dot2(F3.y, w3_.y, a1); \
    a2 = dot2(F3.z, w3_.z, a2); a3 = dot2(F3.w, w3_.w, a3); }

// conv over sorted voxels; each wave owns a CONTIGUOUS run of sorted positions.
// Pair per round: lanes 0..26 probe v, lanes 32..58 probe v+1 (adjacent cells -> hot lines).
// Chunked XCD swizzle keeps each XCD's 32 blocks on one contiguous feature window (~L2-sized).
__global__ __launch_bounds__(BLOCK, 4) void sparse_conv(
    const uint4* __restrict__ fh4, const int* __restrict__ pos, const int* __restrict__ om,
    const float* __restrict__ bias, const uint4* __restrict__ wpk,
    const int* __restrict__ grid, float* __restrict__ out, int n, int run)
{
    extern __shared__ uint4 wlds[];   // [KK*4*COUT] = 110,592 B

    for (int t = threadIdx.x; t < KK*4*COUT; t += BLOCK)
        wlds[t] = wpk[t];
    __syncthreads();

    const int lane = threadIdx.x & 63;
    const int wave = __builtin_amdgcn_readfirstlane((int)(threadIdx.x >> 6));
    const int b0 = blockIdx.x;
    const int sw = ((b0 & 7) << 5) + (b0 >> 3);   // bijective chunked XCD swizzle (256 blocks)
    const int wg = sw * WPB + wave;
    const int lo = wg * run;
    const int hi = min(n, lo + run);

    const float b = bias[lane];
    const int pl = lane & 31;
    const bool prober = pl < KK;
    const int dz = pl / 9 - 1;
    const int dy = (pl / 3) % 3 - 1;
    const int dx = pl % 3 - 1;
    const int hioff = (lane >= 32) ? 1 : 0;

    int nidx = -1;   // declared before lambdas (R1 lesson)

    auto probe = [&](int pb) -> int {
        int r = -1;
        int pv = pb + hioff;
        if (prober && pv < hi) {
            int cell = pos[pv];
            int z = cell / (HH*WW); int rem = cell % (HH*WW);
            int y = rem / WW;       int x = rem % WW;
            int nz = z + dz, ny = y + dy, nx = x + dx;
            if (nz >= 0 && nz < DD && ny >= 0 && ny < HH && nx >= 0 && nx < WW)
                r = grid[(nz*HH + ny)*WW + nx];
        }
        return r;
    };

    auto runvox = [&](uint32_t m, int base, int orig) {
        float a0 = 0.f, a1 = 0.f, a2 = 0.f, a3 = 0.f;
        uint4 A0, A1, A2, A3, B0, B1, B2, B3;
        int kA = __ffs(m) - 1; m &= m - 1;
        int jA = __builtin_amdgcn_readlane(nidx, base + kA);
        LOAD4(A0, A1, A2, A3, jA);
        for (;;) {
            if (!m) { MAC4(A0, A1, A2, A3, kA); break; }
            int kB = __ffs(m) - 1; m &= m - 1;
            int jB = __builtin_amdgcn_readlane(nidx, base + kB);
            LOAD4(B0, B1, B2, B3, jB);         // prefetch next tap
            MAC4(A0, A1, A2, A3, kA);
            if (!m) { MAC4(B0, B1, B2, B3, kB); break; }
            kA = __ffs(m) - 1; m &= m - 1;
            jA = __builtin_amdgcn_readlane(nidx, base + kA);
            LOAD4(A0, A1, A2, A3, jA);
            MAC4(B0, B1, B2, B3, kB);
        }
        float r = b + ((a0 + a1) + (a2 + a3));
        __builtin_nontemporal_store(r, out + (size_t)orig * COUT + lane);
    };

    int v = lo;
    nidx = probe(v);

    while (v < hi) {
        unsigned long long bal = __ballot(nidx >= 0);
        int nidx_next = probe(v + 2);      // next pair's probe hides under MACs

        uint32_t mA = (uint32_t)bal & M27;           // voxel v (self bit always set)
        uint32_t mB = (uint32_t)(bal >> 32) & M27;   // voxel v+1

        runvox(mA, 0, om[v]);
        if (v + 1 < hi) runvox(mB, 32, om[v + 1]);

        v += 2;
        nidx = nidx_next;
    }
}

extern "C" void kernel_launch(void* const* d_in, const int* in_sizes, int n_in,
                              void* d_out, int out_size, void* d_ws, size_t ws_size,
                              hipStream_t stream) {
    const float* feats  = (const float*)d_in[0];
    const int*   coors  = (const int*)d_in[1];
    const float* weight = (const float*)d_in[2];
    const float* bias   = (const float*)d_in[3];
    float*       outp   = (float*)d_out;

    const int n = in_sizes[1] / 4;   // 400000

    char* ws = (char*)d_ws;
    int*   grid = (int*)ws;                                   ws += (size_t)NGRID * 4;
    int*   cnt  = (int*)ws;                                   ws += (size_t)NCHUNK * 4;
    int*   base = (int*)ws;                                   ws += (size_t)NCHUNK * 4;
    uint4* wpk  = (uint4*)ws;                                 ws += (size_t)KK * 4 * COUT * 16;
    int*   pos  = (int*)ws;                                   ws += (size_t)n * 4;
    int*   om   = (int*)ws;                                   ws += (size_t)n * 4;
    uint2* fh   = (uint2*)ws;                                 // n*64 B

    hipMemsetAsync(grid, 0xFF, (size_t)NGRID * 4, stream);
    hipMemsetAsync(cnt, 0, (size_t)NCHUNK * 4, stream);

    scatter_pack<<<(n + KK*4*COUT + 255) / 256, 256, 0, stream>>>(
        (const int4*)coors, weight, grid, cnt, wpk, n);

    scan_chunks<<<1, 1024, 0, stream>>>(cnt, base);

    emit_sort<<<NCHUNK, 1024, 0, stream>>>((const float4*)feats, grid, base, pos, om, fh);

    const int run = (n + TOTW - 1) / TOTW;
    const size_t lds = (size_t)KK * 4 * COUT * sizeof(uint4);  // 110,592 B
    sparse_conv<<<NBLOCKS, BLOCK, lds, stream>>>((const uint4*)fh, pos, om,
                                                 bias, wpk, grid, outp, n, run);
}